// Round 15
// baseline (245.489 us; speedup 1.0000x reference)
//
#include <hip/hip_runtime.h>
#include <hip/hip_bf16.h>

#define NH 16
#define DK 64
#define SEQ 2048
#define DMODEL 1024
#define BATCH 2
#define MROWS (BATCH * SEQ) /* 4096 */

using bf16x8 = __attribute__((ext_vector_type(8))) short;
using f32x4  = __attribute__((ext_vector_type(4))) float;

#define NEGI (-1e30f)
#define QSCALE 0.18033688f  /* 0.125 * log2(e): folds 1/sqrt(dk) and exp->exp2 */

static __device__ __forceinline__ unsigned short f2bf(float x) {
  unsigned u = __builtin_bit_cast(unsigned, x);
  u += 0x7fffu + ((u >> 16) & 1u);   // RNE
  return (unsigned short)(u >> 16);
}
static __device__ __forceinline__ float bf2f(unsigned short h) {
  unsigned u = ((unsigned)h) << 16;
  return __builtin_bit_cast(float, u);
}
// packed f32x2 -> bf16x2 (lo = a, hi = b), single VALU inst
static __device__ __forceinline__ unsigned cvtpk(float a, float b) {
  unsigned r;
  asm("v_cvt_pk_bf16_f32 %0, %1, %2" : "=v"(r) : "v"(a), "v"(b));
  return r;
}

// ------------------------------------------------- converts (f32 -> bf16)
__global__ __launch_bounds__(256) void convert3(const float* __restrict__ s0,
                                                const float* __restrict__ s1,
                                                const float* __restrict__ s2,
                                                unsigned short* __restrict__ d0,
                                                unsigned short* __restrict__ d1,
                                                unsigned short* __restrict__ d2,
                                                long n8, int blkseg) {
  int seg = blockIdx.x / blkseg;
  int ib  = blockIdx.x % blkseg;
  const float* s = seg == 0 ? s0 : (seg == 1 ? s1 : s2);
  unsigned short* d = seg == 0 ? d0 : (seg == 1 ? d1 : d2);
  long i0 = (long)ib * blockDim.x + threadIdx.x;
  long stride = (long)blkseg * blockDim.x;
  for (long i = i0; i < n8; i += stride) {
    const float* p = s + i * 8;
    float4 a = *(const float4*)(p);
    float4 b = *(const float4*)(p + 4);
    bf16x8 v;
    v[0] = (short)f2bf(a.x); v[1] = (short)f2bf(a.y);
    v[2] = (short)f2bf(a.z); v[3] = (short)f2bf(a.w);
    v[4] = (short)f2bf(b.x); v[5] = (short)f2bf(b.y);
    v[6] = (short)f2bf(b.z); v[7] = (short)f2bf(b.w);
    *(bf16x8*)(d + i * 8) = v;
  }
}
__global__ __launch_bounds__(256) void convert4(const float* __restrict__ s0,
                                                const float* __restrict__ s1,
                                                const float* __restrict__ s2,
                                                const float* __restrict__ s3,
                                                unsigned short* __restrict__ d0,
                                                unsigned short* __restrict__ d1,
                                                unsigned short* __restrict__ d2,
                                                unsigned short* __restrict__ d3,
                                                long n8, int blkseg) {
  int seg = blockIdx.x / blkseg;
  int ib  = blockIdx.x % blkseg;
  const float* s = seg == 0 ? s0 : (seg == 1 ? s1 : (seg == 2 ? s2 : s3));
  unsigned short* d = seg == 0 ? d0 : (seg == 1 ? d1 : (seg == 2 ? d2 : d3));
  long i0 = (long)ib * blockDim.x + threadIdx.x;
  long stride = (long)blkseg * blockDim.x;
  for (long i = i0; i < n8; i += stride) {
    const float* p = s + i * 8;
    float4 a = *(const float4*)(p);
    float4 b = *(const float4*)(p + 4);
    bf16x8 v;
    v[0] = (short)f2bf(a.x); v[1] = (short)f2bf(a.y);
    v[2] = (short)f2bf(a.z); v[3] = (short)f2bf(a.w);
    v[4] = (short)f2bf(b.x); v[5] = (short)f2bf(b.y);
    v[6] = (short)f2bf(b.z); v[7] = (short)f2bf(b.w);
    *(bf16x8*)(d + i * 8) = v;
  }
}

// ---------------------------------------------------------------- pack mask
__global__ __launch_bounds__(256) void pack_mask(const int* __restrict__ mask,
                                                 unsigned long long* __restrict__ pm,
                                                 int nwords) {
  int wid  = (blockIdx.x * blockDim.x + threadIdx.x) >> 6;
  int lane = threadIdx.x & 63;
  int nw   = (gridDim.x * blockDim.x) >> 6;
  for (int w = wid; w < nwords; w += nw) {
    int v = mask[(long)w * 64 + lane];
    unsigned long long b = __ballot(v != 0);
    if (lane == 0) pm[w] = b;
  }
}

// ---------------------------------------------------------------- GEMM core
// C = (A @ W^T + bias) * cscale.  Proven 2-barrier skeleton, BK=64.
// mode 0: row-major f32.  mode 1: bf16 scatter [B,H,S,dk].
// mode 2: bf16 scatter-transposed [B,H,dk,S] with packed 8B stores.
#define BK 64
#define LDA2 72   // padded LDS row (elems): 144 B, 16B-aligned

static __device__ __forceinline__ void gemm_body(const unsigned short* __restrict__ A,
                                                 const unsigned short* __restrict__ W,
                                                 const unsigned short* __restrict__ bias,
                                                 void* __restrict__ Cv,
                                                 int mode, float cscale, int bid,
                                                 unsigned short* Al, unsigned short* Bl) {
  const int t    = threadIdx.x;
  const int lane = t & 63;
  const int w    = t >> 6;
  const int wm   = w >> 1, wn = w & 1;
  const int g    = lane >> 4, lr = lane & 15;
  const int nb   = bid & 7;
  const int mb   = bid >> 3;
  const long Abase = (long)mb * 128 * 1024;
  const long Wbase = (long)nb * 128 * 1024;

  f32x4 acc[4][4] = {};

  for (int kt = 0; kt < 1024; kt += BK) {
    __syncthreads();
#pragma unroll
    for (int q = 0; q < 4; ++q) {   // stage 128x64 of A and W (vector loads)
      int id  = q * 256 + t;
      int row = id >> 3;            // 0..127
      int c8  = (id & 7) << 3;      // 0..56
      bf16x8 va = *(const bf16x8*)(A + Abase + (long)row * 1024 + kt + c8);
      bf16x8 vb = *(const bf16x8*)(W + Wbase + (long)row * 1024 + kt + c8);
      *(bf16x8*)(&Al[row * LDA2 + c8]) = va;
      *(bf16x8*)(&Bl[row * LDA2 + c8]) = vb;
    }
    __syncthreads();
#pragma unroll
    for (int kh = 0; kh < 2; ++kh) {   // two k=32 halves per staged tile
      bf16x8 af[4], bfr[4];
#pragma unroll
      for (int i = 0; i < 4; ++i) {
        af[i]  = *(const bf16x8*)(&Al[(wm * 64 + i * 16 + lr) * LDA2 + kh * 32 + g * 8]);
        bfr[i] = *(const bf16x8*)(&Bl[(wn * 64 + i * 16 + lr) * LDA2 + kh * 32 + g * 8]);
      }
#pragma unroll
      for (int i = 0; i < 4; ++i)
#pragma unroll
        for (int j = 0; j < 4; ++j)
          acc[i][j] = __builtin_amdgcn_mfma_f32_16x16x32_bf16(af[i], bfr[j], acc[i][j], 0, 0, 0);
    }
  }

#pragma unroll
  for (int j = 0; j < 4; ++j) {
    int n = nb * 128 + wn * 64 + j * 16 + lr;
    float bv = bf2f(bias[n]);
#pragma unroll
    for (int i = 0; i < 4; ++i) {
      int m0 = mb * 128 + wm * 64 + i * 16 + g * 4;
      float v0 = (acc[i][j][0] + bv) * cscale;
      float v1 = (acc[i][j][1] + bv) * cscale;
      float v2 = (acc[i][j][2] + bv) * cscale;
      float v3 = (acc[i][j][3] + bv) * cscale;
      if (mode == 2) {            // V^T: [B,H,dk,S]; 4 consecutive s -> 8B store
        int b = m0 >> 11, s0 = m0 & (SEQ - 1);
        int h = n >> 6, d = n & (DK - 1);
        uint2 pk;
        pk.x = (unsigned)f2bf(v0) | ((unsigned)f2bf(v1) << 16);
        pk.y = (unsigned)f2bf(v2) | ((unsigned)f2bf(v3) << 16);
        *(uint2*)(&((unsigned short*)Cv)[((long)(b * NH + h) * DK + d) * SEQ + s0]) = pk;
      } else if (mode == 1) {     // [B,H,S,dk]
        int b = m0 >> 11, s0 = m0 & (SEQ - 1);
        int h = n >> 6, d = n & (DK - 1);
        unsigned short* p = &((unsigned short*)Cv)[(((long)(b * NH + h) * SEQ + s0) << 6) + d];
        p[0] = f2bf(v0); p[64] = f2bf(v1); p[128] = f2bf(v2); p[192] = f2bf(v3);
      } else {                    // row-major f32
        float* p = &((float*)Cv)[(long)m0 * DMODEL + n];
        p[0] = v0; p[DMODEL] = v1; p[2 * DMODEL] = v2; p[3 * DMODEL] = v3;
      }
    }
  }
}

// merged Q/K/V projection: 768 blocks, which = blockIdx.x >> 8
__global__ __launch_bounds__(256) void qkv_proj(const unsigned short* __restrict__ Aq,
                                                const unsigned short* __restrict__ Ak,
                                                const unsigned short* __restrict__ Av,
                                                const unsigned short* __restrict__ Wq,
                                                const unsigned short* __restrict__ Wk,
                                                const unsigned short* __restrict__ Wv,
                                                const unsigned short* __restrict__ bq,
                                                const unsigned short* __restrict__ bk,
                                                const unsigned short* __restrict__ bv,
                                                unsigned short* __restrict__ Cq,
                                                unsigned short* __restrict__ Ck,
                                                unsigned short* __restrict__ Cv) {
  __shared__ unsigned short Al[128 * LDA2];
  __shared__ unsigned short Bl[128 * LDA2];
  int which = blockIdx.x >> 8;
  int bid   = blockIdx.x & 255;
  const unsigned short* A = which == 0 ? Aq : (which == 1 ? Ak : Av);
  const unsigned short* W = which == 0 ? Wq : (which == 1 ? Wk : Wv);
  const unsigned short* b = which == 0 ? bq : (which == 1 ? bk : bv);
  unsigned short* C = which == 0 ? Cq : (which == 1 ? Ck : Cv);
  int   mode  = which == 2 ? 2 : 1;
  float scale = which == 0 ? QSCALE : 1.0f;
  gemm_body(A, W, b, C, mode, scale, bid, Al, Bl);
}

__global__ __launch_bounds__(256) void gemm_out(const unsigned short* __restrict__ A,
                                                const unsigned short* __restrict__ W,
                                                const unsigned short* __restrict__ bias,
                                                float* __restrict__ C) {
  __shared__ unsigned short Al[128 * LDA2];
  __shared__ unsigned short Bl[128 * LDA2];
  gemm_body(A, W, bias, C, 0, 1.0f, blockIdx.x, Al, Bl);
}

// ---------------------------------------------------------------- attention
// No-LDS-staging version: kf/vf fragments read DIRECTLY from global (L2-
// resident: K+V = 512 KB per bh, reused by 16 q-blocks; XCD swizzle pins
// 4 bh per XCD = 2 MB working set vs 4 MB L2). Only P lives in LDS and it
// is PER-WAVE private -> no block barriers at all; P write->read ordering
// is a within-wave fence: s_waitcnt lgkmcnt(0) + sched_barrier(0) (rule #18).
// Compute math/layouts identical to twice-validated r13.
#define KVB 64
#define LD 72

__global__ __launch_bounds__(256) void attn(const unsigned short* __restrict__ Q,
                                            const unsigned short* __restrict__ K,
                                            const unsigned short* __restrict__ VT,
                                            const unsigned long long* __restrict__ pm,
                                            unsigned short* __restrict__ O) {
  __shared__ unsigned short Pl[4][32 * LD];    // per-wave 32 q-rows (private)
  const int t    = threadIdx.x;
  const int lane = t & 63;
  const int w    = t >> 6;
  const int g    = lane >> 4, lr = lane & 15;
  // XCD-aware swizzle (bijective: 512 = 8 XCD * 64): 4 bh per XCD
  const int xcd  = blockIdx.x & 7;
  const int idx  = blockIdx.x >> 3;            // 0..63
  const int bh   = xcd * 4 + (idx >> 4);
  const int qb   = idx & 15;
  const int b    = bh >> 4;
  const long base = (long)bh * SEQ * DK;       // same flat size for K and VT
  const int q0   = qb * 128 + w * 32;          // wave's first q-row

  // Q fragments: qf[qh][kh] (B-operand of swapped QK^T)
  bf16x8 qf[2][2];
#pragma unroll
  for (int qh = 0; qh < 2; ++qh) {
    const unsigned short* qp = Q + base + (long)(q0 + qh * 16 + lr) * DK;
    qf[qh][0] = *(const bf16x8*)(qp + g * 8);
    qf[qh][1] = *(const bf16x8*)(qp + 32 + g * 8);
  }
  float mrun[2] = {NEGI, NEGI}, lrun[2] = {0.f, 0.f};  // log2-domain
  f32x4 o[2][4] = {};
  unsigned short* P = &Pl[w][0];

  for (int kt = 0; kt < SEQ / KVB; ++kt) {
    const int kvbase = kt * KVB;

    // swapped scores: C[kv][q]; K fragments straight from global (L2)
    f32x4 sc[2][4];
#pragma unroll
    for (int c = 0; c < 4; ++c) {
      const unsigned short* kp = K + base + (long)(kvbase + c * 16 + lr) * DK;
      bf16x8 kf0 = *(const bf16x8*)(kp + g * 8);
      bf16x8 kf1 = *(const bf16x8*)(kp + 32 + g * 8);
#pragma unroll
      for (int qh = 0; qh < 2; ++qh) {
        f32x4 a = {};
        a = __builtin_amdgcn_mfma_f32_16x16x32_bf16(kf0, qf[qh][0], a, 0, 0, 0);
        a = __builtin_amdgcn_mfma_f32_16x16x32_bf16(kf1, qf[qh][1], a, 0, 0, 0);
        sc[qh][c] = a;
      }
    }

#pragma unroll
    for (int qh = 0; qh < 2; ++qh) {
      const unsigned long long mw = pm[((long)b * SEQ + q0 + qh * 16 + lr) * 32 + kt];
      float s[4][4];
      float mt = NEGI;
#pragma unroll
      for (int c = 0; c < 4; ++c)
#pragma unroll
        for (int r = 0; r < 4; ++r) {
          int kvi = c * 16 + g * 4 + r;
          float v = ((mw >> kvi) & 1ull) ? sc[qh][c][r] : -1e9f;
          s[c][r] = v;
          mt = fmaxf(mt, v);
        }
      mt = fmaxf(mt, __shfl_xor(mt, 16, 64));
      mt = fmaxf(mt, __shfl_xor(mt, 32, 64));

      int need = __any(mt > mrun[qh] + 5.0f);   // defer-max (T13), log2 units
      float mn = mrun[qh], corr = 1.0f;
      if (need) { mn = fmaxf(mrun[qh], mt); corr = __builtin_amdgcn_exp2f(mrun[qh] - mn); mrun[qh] = mn; }

      float pf[4][4];
      float rs = 0.f;
#pragma unroll
      for (int c = 0; c < 4; ++c)
#pragma unroll
        for (int r = 0; r < 4; ++r) {
          float p_ = __builtin_amdgcn_exp2f(s[c][r] - mn);
          pf[c][r] = p_;
          rs += p_;
        }
      rs += __shfl_xor(rs, 16, 64);
      rs += __shfl_xor(rs, 32, 64);

      if (need) {
        lrun[qh] = lrun[qh] * corr + rs;
#pragma unroll
        for (int r = 0; r < 4; ++r) {
          float cq = __shfl(corr, (lane >> 4) * 4 + r, 64);  // corr of q-row g*4+r
#pragma unroll
          for (int dt = 0; dt < 4; ++dt) o[qh][dt][r] *= cq;
        }
      } else {
        lrun[qh] += rs;
      }

      // P store (A-fragment layout): row q-local = qh*16+lr, kv cols
#pragma unroll
      for (int c = 0; c < 4; ++c) {
        uint2 pk;
        pk.x = cvtpk(pf[c][0], pf[c][1]);
        pk.y = cvtpk(pf[c][2], pf[c][3]);
        *(uint2*)(&P[(qh * 16 + lr) * LD + c * 16 + g * 4]) = pk;
      }
    }
    // within-wave fence: P ds_writes complete + no hoisting of P ds_reads
    asm volatile("s_waitcnt lgkmcnt(0)" ::: "memory");
    __builtin_amdgcn_sched_barrier(0);

    // PV: P from per-wave LDS; V^T fragments straight from global (L2)
#pragma unroll
    for (int c32 = 0; c32 < 2; ++c32) {
      bf16x8 pf0 = *(const bf16x8*)(&P[lr * LD + c32 * 32 + g * 8]);
      bf16x8 pf1 = *(const bf16x8*)(&P[(16 + lr) * LD + c32 * 32 + g * 8]);
#pragma unroll
      for (int dt = 0; dt < 4; ++dt) {
        bf16x8 vf = *(const bf16x8*)(VT + base + (long)(dt * 16 + lr) * SEQ
                                     + kvbase + c32 * 32 + g * 8);
        o[0][dt] = __builtin_amdgcn_mfma_f32_16x16x32_bf16(pf0, vf, o[0][dt], 0, 0, 0);
        o[1][dt] = __builtin_amdgcn_mfma_f32_16x16x32_bf16(pf1, vf, o[1][dt], 0, 0, 0);
      }
    }
    // within-wave fence: P ds_reads complete before next tile's P ds_writes
    asm volatile("s_waitcnt lgkmcnt(0)" ::: "memory");
    __builtin_amdgcn_sched_barrier(0);
  }
#pragma unroll
  for (int qh = 0; qh < 2; ++qh) {
    float inv = 1.0f / lrun[qh];
#pragma unroll
    for (int r = 0; r < 4; ++r) {
      float iq = __shfl(inv, (lane >> 4) * 4 + r, 64);
      int q = q0 + qh * 16 + g * 4 + r;
      unsigned short* op = O + ((long)(b * SEQ + q) * DMODEL) + (bh & 15) * DK;
#pragma unroll
      for (int dt = 0; dt < 4; ++dt) op[dt * 16 + lr] = f2bf(o[qh][dt][r] * iq);
    }
  }
}

// ---------------------------------------------------------------- launch
extern "C" void kernel_launch(void* const* d_in, const int* in_sizes, int n_in,
                              void* d_out, int out_size, void* d_ws, size_t ws_size,
                              hipStream_t stream) {
  const int* maskp = (const int*)d_in[3];
  float* out = (float*)d_out;

  char* ws = (char*)d_ws;
  const long MB = 1 << 20;
  unsigned long long* pm = (unsigned long long*)ws;             // 1 MB
  unsigned short* Qc  = (unsigned short*)(ws + 1 * MB);         // 8 MB each
  unsigned short* Kc  = (unsigned short*)(ws + 9 * MB);
  unsigned short* Vc  = (unsigned short*)(ws + 17 * MB);
  unsigned short* Wqc = (unsigned short*)(ws + 25 * MB);        // 2 MB each
  unsigned short* Wkc = (unsigned short*)(ws + 27 * MB);
  unsigned short* Wvc = (unsigned short*)(ws + 29 * MB);
  unsigned short* Woc = (unsigned short*)(ws + 31 * MB);
  unsigned short* bqc = (unsigned short*)(ws + 33 * MB);        // 2 KB each
  unsigned short* bkc = (unsigned short*)(ws + 33 * MB + 4096);
  unsigned short* bvc = (unsigned short*)(ws + 33 * MB + 8192);
  unsigned short* boc = (unsigned short*)(ws + 33 * MB + 12288);
  unsigned short* Qb  = (unsigned short*)(ws + 35 * MB);        // 8 MB each
  unsigned short* Kb  = (unsigned short*)(ws + 43 * MB);
  unsigned short* Vb  = (unsigned short*)(ws + 51 * MB);        // holds V^T
  unsigned short* Ab  = (unsigned short*)(ws + 59 * MB);

  const long nQKV8 = (long)MROWS * DMODEL / 8;   // 524288
  const long nW8   = (long)DMODEL * DMODEL / 8;  // 131072
  convert3<<<1536, 256, 0, stream>>>((const float*)d_in[0], (const float*)d_in[1],
                                     (const float*)d_in[2], Qc, Kc, Vc, nQKV8, 512);
  convert4<<<512, 256, 0, stream>>>((const float*)d_in[4], (const float*)d_in[6],
                                    (const float*)d_in[8], (const float*)d_in[10],
                                    Wqc, Wkc, Wvc, Woc, nW8, 128);
  convert4<<<4, 256, 0, stream>>>((const float*)d_in[5], (const float*)d_in[7],
                                  (const float*)d_in[9], (const float*)d_in[11],
                                  bqc, bkc, bvc, boc, DMODEL / 8, 1);

  const int nwords = BATCH * SEQ * (SEQ / 64);  // 131072
  pack_mask<<<512, 256, 0, stream>>>(maskp, pm, nwords);

  qkv_proj<<<768, 256, 0, stream>>>(Qc, Kc, Vc, Wqc, Wkc, Wvc,
                                    bqc, bkc, bvc, Qb, Kb, Vb);

  attn<<<BATCH * NH * (SEQ / 128), 256, 0, stream>>>(Qb, Kb, Vb, pm, Ab);

  gemm_out<<<256, 256, 0, stream>>>(Ab, Woc, boc, out);
}

// Round 16
// 221.434 us; speedup vs baseline: 1.1086x; 1.1086x over previous
//
#include <hip/hip_runtime.h>
#include <hip/hip_bf16.h>

#define NH 16
#define DK 64
#define SEQ 2048
#define DMODEL 1024
#define BATCH 2
#define MROWS (BATCH * SEQ) /* 4096 */

using bf16x8 = __attribute__((ext_vector_type(8))) short;
using f32x4  = __attribute__((ext_vector_type(4))) float;
using f32x16 = __attribute__((ext_vector_type(16))) float;
using i32x2  = __attribute__((ext_vector_type(2))) int;

#define NEGI (-1e30f)
#define QSCALE 0.18033688f  /* 0.125 * log2(e): folds 1/sqrt(dk) and exp->exp2 */

static __device__ __forceinline__ unsigned short f2bf(float x) {
  unsigned u = __builtin_bit_cast(unsigned, x);
  u += 0x7fffu + ((u >> 16) & 1u);   // RNE
  return (unsigned short)(u >> 16);
}
static __device__ __forceinline__ float bf2f(unsigned short h) {
  unsigned u = ((unsigned)h) << 16;
  return __builtin_bit_cast(float, u);
}
// packed f32x2 -> bf16x2 (lo = a, hi = b), single VALU inst
static __device__ __forceinline__ unsigned cvtpk(float a, float b) {
  unsigned r;
  asm("v_cvt_pk_bf16_f32 %0, %1, %2" : "=v"(r) : "v"(a), "v"(b));
  return r;
}

// ------------------------------------------------- converts (f32 -> bf16)
__global__ __launch_bounds__(256) void convert3(const float* __restrict__ s0,
                                                const float* __restrict__ s1,
                                                const float* __restrict__ s2,
                                                unsigned short* __restrict__ d0,
                                                unsigned short* __restrict__ d1,
                                                unsigned short* __restrict__ d2,
                                                long n8, int blkseg) {
  int seg = blockIdx.x / blkseg;
  int ib  = blockIdx.x % blkseg;
  const float* s = seg == 0 ? s0 : (seg == 1 ? s1 : s2);
  unsigned short* d = seg == 0 ? d0 : (seg == 1 ? d1 : d2);
  long i0 = (long)ib * blockDim.x + threadIdx.x;
  long stride = (long)blkseg * blockDim.x;
  for (long i = i0; i < n8; i += stride) {
    const float* p = s + i * 8;
    float4 a = *(const float4*)(p);
    float4 b = *(const float4*)(p + 4);
    bf16x8 v;
    v[0] = (short)f2bf(a.x); v[1] = (short)f2bf(a.y);
    v[2] = (short)f2bf(a.z); v[3] = (short)f2bf(a.w);
    v[4] = (short)f2bf(b.x); v[5] = (short)f2bf(b.y);
    v[6] = (short)f2bf(b.z); v[7] = (short)f2bf(b.w);
    *(bf16x8*)(d + i * 8) = v;
  }
}
__global__ __launch_bounds__(256) void convert4(const float* __restrict__ s0,
                                                const float* __restrict__ s1,
                                                const float* __restrict__ s2,
                                                const float* __restrict__ s3,
                                                unsigned short* __restrict__ d0,
                                                unsigned short* __restrict__ d1,
                                                unsigned short* __restrict__ d2,
                                                unsigned short* __restrict__ d3,
                                                long n8, int blkseg) {
  int seg = blockIdx.x / blkseg;
  int ib  = blockIdx.x % blkseg;
  const float* s = seg == 0 ? s0 : (seg == 1 ? s1 : (seg == 2 ? s2 : s3));
  unsigned short* d = seg == 0 ? d0 : (seg == 1 ? d1 : (seg == 2 ? d2 : d3));
  long i0 = (long)ib * blockDim.x + threadIdx.x;
  long stride = (long)blkseg * blockDim.x;
  for (long i = i0; i < n8; i += stride) {
    const float* p = s + i * 8;
    float4 a = *(const float4*)(p);
    float4 b = *(const float4*)(p + 4);
    bf16x8 v;
    v[0] = (short)f2bf(a.x); v[1] = (short)f2bf(a.y);
    v[2] = (short)f2bf(a.z); v[3] = (short)f2bf(a.w);
    v[4] = (short)f2bf(b.x); v[5] = (short)f2bf(b.y);
    v[6] = (short)f2bf(b.z); v[7] = (short)f2bf(b.w);
    *(bf16x8*)(d + i * 8) = v;
  }
}

// ---------------------------------------------------------------- pack mask
__global__ __launch_bounds__(256) void pack_mask(const int* __restrict__ mask,
                                                 unsigned long long* __restrict__ pm,
                                                 int nwords) {
  int wid  = (blockIdx.x * blockDim.x + threadIdx.x) >> 6;
  int lane = threadIdx.x & 63;
  int nw   = (gridDim.x * blockDim.x) >> 6;
  for (int w = wid; w < nwords; w += nw) {
    int v = mask[(long)w * 64 + lane];
    unsigned long long b = __ballot(v != 0);
    if (lane == 0) pm[w] = b;
  }
}

// ---------------------------------------------------------------- GEMM core
// C = (A @ W^T + bias) * cscale.  Proven 2-barrier skeleton, BK=64.
// mode 0: row-major f32.  mode 1: bf16 scatter [B,H,S,dk].
// mode 2: bf16 scatter-transposed [B,H,dk,S] with packed 8B stores.
#define BK 64
#define LDA2 72   // padded LDS row (elems): 144 B, 16B-aligned

static __device__ __forceinline__ void gemm_body(const unsigned short* __restrict__ A,
                                                 const unsigned short* __restrict__ W,
                                                 const unsigned short* __restrict__ bias,
                                                 void* __restrict__ Cv,
                                                 int mode, float cscale, int bid,
                                                 unsigned short* Al, unsigned short* Bl) {
  const int t    = threadIdx.x;
  const int lane = t & 63;
  const int w    = t >> 6;
  const int wm   = w >> 1, wn = w & 1;
  const int g    = lane >> 4, lr = lane & 15;
  const int nb   = bid & 7;
  const int mb   = bid >> 3;
  const long Abase = (long)mb * 128 * 1024;
  const long Wbase = (long)nb * 128 * 1024;

  f32x4 acc[4][4] = {};

  for (int kt = 0; kt < 1024; kt += BK) {
    __syncthreads();
#pragma unroll
    for (int q = 0; q < 4; ++q) {   // stage 128x64 of A and W (vector loads)
      int id  = q * 256 + t;
      int row = id >> 3;            // 0..127
      int c8  = (id & 7) << 3;      // 0..56
      bf16x8 va = *(const bf16x8*)(A + Abase + (long)row * 1024 + kt + c8);
      bf16x8 vb = *(const bf16x8*)(W + Wbase + (long)row * 1024 + kt + c8);
      *(bf16x8*)(&Al[row * LDA2 + c8]) = va;
      *(bf16x8*)(&Bl[row * LDA2 + c8]) = vb;
    }
    __syncthreads();
#pragma unroll
    for (int kh = 0; kh < 2; ++kh) {   // two k=32 halves per staged tile
      bf16x8 af[4], bfr[4];
#pragma unroll
      for (int i = 0; i < 4; ++i) {
        af[i]  = *(const bf16x8*)(&Al[(wm * 64 + i * 16 + lr) * LDA2 + kh * 32 + g * 8]);
        bfr[i] = *(const bf16x8*)(&Bl[(wn * 64 + i * 16 + lr) * LDA2 + kh * 32 + g * 8]);
      }
#pragma unroll
      for (int i = 0; i < 4; ++i)
#pragma unroll
        for (int j = 0; j < 4; ++j)
          acc[i][j] = __builtin_amdgcn_mfma_f32_16x16x32_bf16(af[i], bfr[j], acc[i][j], 0, 0, 0);
    }
  }

#pragma unroll
  for (int j = 0; j < 4; ++j) {
    int n = nb * 128 + wn * 64 + j * 16 + lr;
    float bv = bf2f(bias[n]);
#pragma unroll
    for (int i = 0; i < 4; ++i) {
      int m0 = mb * 128 + wm * 64 + i * 16 + g * 4;
      float v0 = (acc[i][j][0] + bv) * cscale;
      float v1 = (acc[i][j][1] + bv) * cscale;
      float v2 = (acc[i][j][2] + bv) * cscale;
      float v3 = (acc[i][j][3] + bv) * cscale;
      if (mode == 2) {            // V^T: [B,H,dk,S]; 4 consecutive s -> 8B store
        int b = m0 >> 11, s0 = m0 & (SEQ - 1);
        int h = n >> 6, d = n & (DK - 1);
        uint2 pk;
        pk.x = (unsigned)f2bf(v0) | ((unsigned)f2bf(v1) << 16);
        pk.y = (unsigned)f2bf(v2) | ((unsigned)f2bf(v3) << 16);
        *(uint2*)(&((unsigned short*)Cv)[((long)(b * NH + h) * DK + d) * SEQ + s0]) = pk;
      } else if (mode == 1) {     // [B,H,S,dk]
        int b = m0 >> 11, s0 = m0 & (SEQ - 1);
        int h = n >> 6, d = n & (DK - 1);
        unsigned short* p = &((unsigned short*)Cv)[(((long)(b * NH + h) * SEQ + s0) << 6) + d];
        p[0] = f2bf(v0); p[64] = f2bf(v1); p[128] = f2bf(v2); p[192] = f2bf(v3);
      } else {                    // row-major f32
        float* p = &((float*)Cv)[(long)m0 * DMODEL + n];
        p[0] = v0; p[DMODEL] = v1; p[2 * DMODEL] = v2; p[3 * DMODEL] = v3;
      }
    }
  }
}

// merged Q/K/V projection: 768 blocks, which = blockIdx.x >> 8
__global__ __launch_bounds__(256) void qkv_proj(const unsigned short* __restrict__ Aq,
                                                const unsigned short* __restrict__ Ak,
                                                const unsigned short* __restrict__ Av,
                                                const unsigned short* __restrict__ Wq,
                                                const unsigned short* __restrict__ Wk,
                                                const unsigned short* __restrict__ Wv,
                                                const unsigned short* __restrict__ bq,
                                                const unsigned short* __restrict__ bk,
                                                const unsigned short* __restrict__ bv,
                                                unsigned short* __restrict__ Cq,
                                                unsigned short* __restrict__ Ck,
                                                unsigned short* __restrict__ Cv) {
  __shared__ unsigned short Al[128 * LDA2];
  __shared__ unsigned short Bl[128 * LDA2];
  int which = blockIdx.x >> 8;
  int bid   = blockIdx.x & 255;
  const unsigned short* A = which == 0 ? Aq : (which == 1 ? Ak : Av);
  const unsigned short* W = which == 0 ? Wq : (which == 1 ? Wk : Wv);
  const unsigned short* b = which == 0 ? bq : (which == 1 ? bk : bv);
  unsigned short* C = which == 0 ? Cq : (which == 1 ? Ck : Cv);
  int   mode  = which == 2 ? 2 : 1;
  float scale = which == 0 ? QSCALE : 1.0f;
  gemm_body(A, W, b, C, mode, scale, bid, Al, Bl);
}

__global__ __launch_bounds__(256) void gemm_out(const unsigned short* __restrict__ A,
                                                const unsigned short* __restrict__ W,
                                                const unsigned short* __restrict__ bias,
                                                float* __restrict__ C) {
  __shared__ unsigned short Al[128 * LDA2];
  __shared__ unsigned short Bl[128 * LDA2];
  gemm_body(A, W, bias, C, 0, 1.0f, blockIdx.x, Al, Bl);
}

// ---------------------------------------------------------------- attention
// 32x32x16 MFMA version. Swapped QK^T: D[kv][q] (C/D: col=lane&31,
// row=(r&3)+8*(r>>2)+4*(lane>>5) — HW-verified mapping). Each lane owns one
// q-row (q=lane&31) -> softmax via shfl_xor(32) combines; P rebuilt fully
// in registers (cvtpk + permlane32_swap) -> NO P LDS, 2 barriers/tile
// (the proven gemm skeleton). K/V staging identical to r13.
#define KVB 64
#define LD 72

__global__ __launch_bounds__(256) void attn(const unsigned short* __restrict__ Q,
                                            const unsigned short* __restrict__ K,
                                            const unsigned short* __restrict__ VT,
                                            const unsigned long long* __restrict__ pm,
                                            unsigned short* __restrict__ O) {
  __shared__ unsigned short Kl[KVB * LD];
  __shared__ unsigned short Vt[DK * LD];       // Vt[d][kv]
  const int t    = threadIdx.x;
  const int lane = t & 63;
  const int w    = t >> 6;
  const int ln31 = lane & 31;                  // q (QK col), d (PV col), row idx
  const int hi   = lane >> 5;
  const int qb   = blockIdx.x & 15;            // SEQ/128 = 16 q-blocks
  const int bh   = blockIdx.x >> 4;
  const int b    = bh >> 4, h = bh & 15;
  const long base = (long)bh * SEQ * DK;       // same flat size for K and VT
  const int q0   = qb * 128 + w * 32;          // wave's first q-row

  // Q B-frags: qfr[c] elem e <-> k = c*16 + hi*8 + e, col q = ln31
  bf16x8 qfr[4];
  {
    const unsigned short* qp = Q + base + (long)(q0 + ln31) * DK + hi * 8;
#pragma unroll
    for (int c = 0; c < 4; ++c) qfr[c] = *(const bf16x8*)(qp + c * 16);
  }
  float mrun = NEGI, lrun = 0.f;               // per-q (lane&31), log2-domain
  f32x16 o0 = {}, o1 = {};                     // PV acc: d-tile 0/1
  const unsigned long long* pmrow = pm + ((long)b * SEQ + q0 + ln31) * 32;

  for (int kt = 0; kt < SEQ / KVB; ++kt) {
    const int kvbase = kt * KVB;
    __syncthreads();
    // stage K rows [kv][64] and V^T rows [d][kv] — b128 (r13-proven)
#pragma unroll
    for (int p = 0; p < 2; ++p) {
      int id  = p * 256 + t;
      int row = id >> 3;
      int c8  = (id & 7) << 3;
      *(bf16x8*)(&Kl[row * LD + c8]) =
          *(const bf16x8*)(K + base + (long)(kvbase + row) * DK + c8);
      *(bf16x8*)(&Vt[row * LD + c8]) =
          *(const bf16x8*)(VT + base + (long)row * SEQ + kvbase + c8);
    }
    __syncthreads();

    // QK^T: two 32x32 kv-subtiles, K=64 in 4 chunks
    f32x16 sc0 = {}, sc1 = {};
#pragma unroll
    for (int c = 0; c < 4; ++c) {
      bf16x8 kf0 = *(const bf16x8*)(&Kl[ln31 * LD + c * 16 + hi * 8]);
      bf16x8 kf1 = *(const bf16x8*)(&Kl[(32 + ln31) * LD + c * 16 + hi * 8]);
      sc0 = __builtin_amdgcn_mfma_f32_32x32x16_bf16(kf0, qfr[c], sc0, 0, 0, 0);
      sc1 = __builtin_amdgcn_mfma_f32_32x32x16_bf16(kf1, qfr[c], sc1, 0, 0, 0);
    }

    // mask + row max (in place)
    const unsigned long long mw = pmrow[kt];
    float mt = NEGI;
#pragma unroll
    for (int r = 0; r < 16; ++r) {
      int kvl = (r & 3) + 8 * (r >> 2) + 4 * hi;
      float v0 = ((mw >> kvl) & 1ull) ? sc0[r] : -1e9f;
      float v1 = ((mw >> (32 + kvl)) & 1ull) ? sc1[r] : -1e9f;
      sc0[r] = v0; sc1[r] = v1;
      mt = fmaxf(mt, fmaxf(v0, v1));
    }
    mt = fmaxf(mt, __shfl_xor(mt, 32, 64));

    int need = __any(mt > mrun + 5.0f);        // defer-max (T13)
    float mn = mrun, corr = 1.0f;
    if (need) { mn = fmaxf(mrun, mt); corr = __builtin_amdgcn_exp2f(mrun - mn); mrun = mn; }

    float rs = 0.f;
#pragma unroll
    for (int r = 0; r < 16; ++r) {
      sc0[r] = __builtin_amdgcn_exp2f(sc0[r] - mn);
      sc1[r] = __builtin_amdgcn_exp2f(sc1[r] - mn);
      rs += sc0[r] + sc1[r];
    }
    rs += __shfl_xor(rs, 32, 64);

    if (need) {
      lrun = lrun * corr + rs;
#pragma unroll
      for (int r = 0; r < 16; ++r) {
        int qq = (r & 3) + 8 * (r >> 2) + 4 * hi;
        float cq = __shfl(corr, qq, 64);
        o0[r] *= cq; o1[r] *= cq;
      }
    } else {
      lrun += rs;
    }

    // pack P -> 4 A-frags (kv chunks of 16) fully in registers
    bf16x8 pa[4];
#pragma unroll
    for (int sub = 0; sub < 2; ++sub) {
      unsigned wv[8];
#pragma unroll
      for (int j = 0; j < 8; ++j) {
        float a  = (sub == 0) ? sc0[2 * j]     : sc1[2 * j];
        float c_ = (sub == 0) ? sc0[2 * j + 1] : sc1[2 * j + 1];
        wv[j] = cvtpk(a, c_);
      }
#if __has_builtin(__builtin_amdgcn_permlane32_swap)
      i32x2 sA = __builtin_amdgcn_permlane32_swap((int)wv[0], (int)wv[2], false, false);
      i32x2 sB = __builtin_amdgcn_permlane32_swap((int)wv[1], (int)wv[3], false, false);
      i32x2 sC = __builtin_amdgcn_permlane32_swap((int)wv[4], (int)wv[6], false, false);
      i32x2 sD = __builtin_amdgcn_permlane32_swap((int)wv[5], (int)wv[7], false, false);
      uint4 f0 = {(unsigned)sA.x, (unsigned)sB.x, (unsigned)sA.y, (unsigned)sB.y};
      uint4 f1 = {(unsigned)sC.x, (unsigned)sD.x, (unsigned)sC.y, (unsigned)sD.y};
#else
      unsigned x0 = __shfl_xor(wv[0], 32, 64), x1 = __shfl_xor(wv[1], 32, 64);
      unsigned x2 = __shfl_xor(wv[2], 32, 64), x3 = __shfl_xor(wv[3], 32, 64);
      unsigned x4 = __shfl_xor(wv[4], 32, 64), x5 = __shfl_xor(wv[5], 32, 64);
      unsigned x6 = __shfl_xor(wv[6], 32, 64), x7 = __shfl_xor(wv[7], 32, 64);
      uint4 f0 = {hi ? x2 : wv[0], hi ? x3 : wv[1], hi ? wv[2] : x0, hi ? wv[3] : x1};
      uint4 f1 = {hi ? x6 : wv[4], hi ? x7 : wv[5], hi ? wv[6] : x4, hi ? wv[7] : x5};
#endif
      pa[sub * 2]     = __builtin_bit_cast(bf16x8, f0);
      pa[sub * 2 + 1] = __builtin_bit_cast(bf16x8, f1);
    }

    // PV: O[q][d], B=V from Vt rows (d), kv chunks of 16
#pragma unroll
    for (int c = 0; c < 4; ++c) {
      bf16x8 vf0 = *(const bf16x8*)(&Vt[ln31 * LD + c * 16 + hi * 8]);
      bf16x8 vf1 = *(const bf16x8*)(&Vt[(32 + ln31) * LD + c * 16 + hi * 8]);
      o0 = __builtin_amdgcn_mfma_f32_32x32x16_bf16(pa[c], vf0, o0, 0, 0, 0);
      o1 = __builtin_amdgcn_mfma_f32_32x32x16_bf16(pa[c], vf1, o1, 0, 0, 0);
    }
  }

  // epilogue: normalize + store. o reg r: q=(r&3)+8*(r>>2)+4*hi, d=dtile*32+ln31
  float inv = 1.0f / lrun;
#pragma unroll
  for (int r = 0; r < 16; ++r) {
    int qq = (r & 3) + 8 * (r >> 2) + 4 * hi;
    float iq = __shfl(inv, qq, 64);
    unsigned short* op = O + ((long)(b * SEQ + q0 + qq) * DMODEL) + h * DK + ln31;
    op[0]  = f2bf(o0[r] * iq);
    op[32] = f2bf(o1[r] * iq);
  }
}

// ---------------------------------------------------------------- launch
extern "C" void kernel_launch(void* const* d_in, const int* in_sizes, int n_in,
                              void* d_out, int out_size, void* d_ws, size_t ws_size,
                              hipStream_t stream) {
  const int* maskp = (const int*)d_in[3];
  float* out = (float*)d_out;

  char* ws = (char*)d_ws;
  const long MB = 1 << 20;
  unsigned long long* pm = (unsigned long long*)ws;             // 1 MB
  unsigned short* Qc  = (unsigned short*)(ws + 1 * MB);         // 8 MB each
  unsigned short* Kc  = (unsigned short*)(ws + 9 * MB);
  unsigned short* Vc  = (unsigned short*)(ws + 17 * MB);
  unsigned short* Wqc = (unsigned short*)(ws + 25 * MB);        // 2 MB each
  unsigned short* Wkc = (unsigned short*)(ws + 27 * MB);
  unsigned short* Wvc = (unsigned short*)(ws + 29 * MB);
  unsigned short* Woc = (unsigned short*)(ws + 31 * MB);
  unsigned short* bqc = (unsigned short*)(ws + 33 * MB);        // 2 KB each
  unsigned short* bkc = (unsigned short*)(ws + 33 * MB + 4096);
  unsigned short* bvc = (unsigned short*)(ws + 33 * MB + 8192);
  unsigned short* boc = (unsigned short*)(ws + 33 * MB + 12288);
  unsigned short* Qb  = (unsigned short*)(ws + 35 * MB);        // 8 MB each
  unsigned short* Kb  = (unsigned short*)(ws + 43 * MB);
  unsigned short* Vb  = (unsigned short*)(ws + 51 * MB);        // holds V^T
  unsigned short* Ab  = (unsigned short*)(ws + 59 * MB);

  const long nQKV8 = (long)MROWS * DMODEL / 8;   // 524288
  const long nW8   = (long)DMODEL * DMODEL / 8;  // 131072
  convert3<<<1536, 256, 0, stream>>>((const float*)d_in[0], (const float*)d_in[1],
                                     (const float*)d_in[2], Qc, Kc, Vc, nQKV8, 512);
  convert4<<<512, 256, 0, stream>>>((const float*)d_in[4], (const float*)d_in[6],
                                    (const float*)d_in[8], (const float*)d_in[10],
                                    Wqc, Wkc, Wvc, Woc, nW8, 128);
  convert4<<<4, 256, 0, stream>>>((const float*)d_in[5], (const float*)d_in[7],
                                  (const float*)d_in[9], (const float*)d_in[11],
                                  bqc, bkc, bvc, boc, DMODEL / 8, 1);

  const int nwords = BATCH * SEQ * (SEQ / 64);  // 131072
  pack_mask<<<512, 256, 0, stream>>>(maskp, pm, nwords);

  qkv_proj<<<768, 256, 0, stream>>>(Qc, Kc, Vc, Wqc, Wkc, Wvc,
                                    bqc, bkc, bvc, Qb, Kb, Vb);

  attn<<<BATCH * NH * (SEQ / 128), 256, 0, stream>>>(Qb, Kb, Vb, pm, Ab);

  gemm_out<<<256, 256, 0, stream>>>(Ab, Woc, boc, out);
}

// Round 17
// 196.072 us; speedup vs baseline: 1.2520x; 1.1293x over previous
//
#include <hip/hip_runtime.h>
#include <hip/hip_bf16.h>

#define NH 16
#define DK 64
#define SEQ 2048
#define DMODEL 1024
#define BATCH 2
#define MROWS (BATCH * SEQ) /* 4096 */

using bf16x8 = __attribute__((ext_vector_type(8))) short;
using f32x4  = __attribute__((ext_vector_type(4))) float;

#define NEGI (-1e30f)
#define QSCALE 0.18033688f  /* 0.125 * log2(e): folds 1/sqrt(dk) and exp->exp2 */

static __device__ __forceinline__ unsigned short f2bf(float x) {
  unsigned u = __builtin_bit_cast(unsigned, x);
  u += 0x7fffu + ((u >> 16) & 1u);   // RNE
  return (unsigned short)(u >> 16);
}
static __device__ __forceinline__ float bf2f(unsigned short h) {
  unsigned u = ((unsigned)h) << 16;
  return __builtin_bit_cast(float, u);
}
// packed f32x2 -> bf16x2 (lo = a, hi = b), single VALU inst
static __device__ __forceinline__ unsigned cvtpk(float a, float b) {
  unsigned r;
  asm("v_cvt_pk_bf16_f32 %0, %1, %2" : "=v"(r) : "v"(a), "v"(b));
  return r;
}

// ------------------------------------------------- converts (f32 -> bf16)
__global__ __launch_bounds__(256) void convert3(const float* __restrict__ s0,
                                                const float* __restrict__ s1,
                                                const float* __restrict__ s2,
                                                unsigned short* __restrict__ d0,
                                                unsigned short* __restrict__ d1,
                                                unsigned short* __restrict__ d2,
                                                long n8, int blkseg) {
  int seg = blockIdx.x / blkseg;
  int ib  = blockIdx.x % blkseg;
  const float* s = seg == 0 ? s0 : (seg == 1 ? s1 : s2);
  unsigned short* d = seg == 0 ? d0 : (seg == 1 ? d1 : d2);
  long i0 = (long)ib * blockDim.x + threadIdx.x;
  long stride = (long)blkseg * blockDim.x;
  for (long i = i0; i < n8; i += stride) {
    const float* p = s + i * 8;
    float4 a = *(const float4*)(p);
    float4 b = *(const float4*)(p + 4);
    bf16x8 v;
    v[0] = (short)f2bf(a.x); v[1] = (short)f2bf(a.y);
    v[2] = (short)f2bf(a.z); v[3] = (short)f2bf(a.w);
    v[4] = (short)f2bf(b.x); v[5] = (short)f2bf(b.y);
    v[6] = (short)f2bf(b.z); v[7] = (short)f2bf(b.w);
    *(bf16x8*)(d + i * 8) = v;
  }
}
__global__ __launch_bounds__(256) void convert4(const float* __restrict__ s0,
                                                const float* __restrict__ s1,
                                                const float* __restrict__ s2,
                                                const float* __restrict__ s3,
                                                unsigned short* __restrict__ d0,
                                                unsigned short* __restrict__ d1,
                                                unsigned short* __restrict__ d2,
                                                unsigned short* __restrict__ d3,
                                                long n8, int blkseg) {
  int seg = blockIdx.x / blkseg;
  int ib  = blockIdx.x % blkseg;
  const float* s = seg == 0 ? s0 : (seg == 1 ? s1 : (seg == 2 ? s2 : s3));
  unsigned short* d = seg == 0 ? d0 : (seg == 1 ? d1 : (seg == 2 ? d2 : d3));
  long i0 = (long)ib * blockDim.x + threadIdx.x;
  long stride = (long)blkseg * blockDim.x;
  for (long i = i0; i < n8; i += stride) {
    const float* p = s + i * 8;
    float4 a = *(const float4*)(p);
    float4 b = *(const float4*)(p + 4);
    bf16x8 v;
    v[0] = (short)f2bf(a.x); v[1] = (short)f2bf(a.y);
    v[2] = (short)f2bf(a.z); v[3] = (short)f2bf(a.w);
    v[4] = (short)f2bf(b.x); v[5] = (short)f2bf(b.y);
    v[6] = (short)f2bf(b.z); v[7] = (short)f2bf(b.w);
    *(bf16x8*)(d + i * 8) = v;
  }
}

// ---------------------------------------------------------------- pack mask
__global__ __launch_bounds__(256) void pack_mask(const int* __restrict__ mask,
                                                 unsigned long long* __restrict__ pm,
                                                 int nwords) {
  int wid  = (blockIdx.x * blockDim.x + threadIdx.x) >> 6;
  int lane = threadIdx.x & 63;
  int nw   = (gridDim.x * blockDim.x) >> 6;
  for (int w = wid; w < nwords; w += nw) {
    int v = mask[(long)w * 64 + lane];
    unsigned long long b = __ballot(v != 0);
    if (lane == 0) pm[w] = b;
  }
}

// ---------------------------------------------------------------- GEMM core
// C = (A @ W^T + bias) * cscale.  Proven 2-barrier skeleton, BK=64.
// mode 0: row-major f32.  mode 1: bf16 scatter [B,H,S,dk].
// mode 2: bf16 scatter-transposed [B,H,dk,S] with packed 8B stores.
#define BK 64
#define LDA2 72   // padded LDS row (elems): 144 B, 16B-aligned

static __device__ __forceinline__ void gemm_body(const unsigned short* __restrict__ A,
                                                 const unsigned short* __restrict__ W,
                                                 const unsigned short* __restrict__ bias,
                                                 void* __restrict__ Cv,
                                                 int mode, float cscale, int bid,
                                                 unsigned short* Al, unsigned short* Bl) {
  const int t    = threadIdx.x;
  const int lane = t & 63;
  const int w    = t >> 6;
  const int wm   = w >> 1, wn = w & 1;
  const int g    = lane >> 4, lr = lane & 15;
  const int nb   = bid & 7;
  const int mb   = bid >> 3;
  const long Abase = (long)mb * 128 * 1024;
  const long Wbase = (long)nb * 128 * 1024;

  f32x4 acc[4][4] = {};

  for (int kt = 0; kt < 1024; kt += BK) {
    __syncthreads();
#pragma unroll
    for (int q = 0; q < 4; ++q) {   // stage 128x64 of A and W (vector loads)
      int id  = q * 256 + t;
      int row = id >> 3;            // 0..127
      int c8  = (id & 7) << 3;      // 0..56
      bf16x8 va = *(const bf16x8*)(A + Abase + (long)row * 1024 + kt + c8);
      bf16x8 vb = *(const bf16x8*)(W + Wbase + (long)row * 1024 + kt + c8);
      *(bf16x8*)(&Al[row * LDA2 + c8]) = va;
      *(bf16x8*)(&Bl[row * LDA2 + c8]) = vb;
    }
    __syncthreads();
#pragma unroll
    for (int kh = 0; kh < 2; ++kh) {   // two k=32 halves per staged tile
      bf16x8 af[4], bfr[4];
#pragma unroll
      for (int i = 0; i < 4; ++i) {
        af[i]  = *(const bf16x8*)(&Al[(wm * 64 + i * 16 + lr) * LDA2 + kh * 32 + g * 8]);
        bfr[i] = *(const bf16x8*)(&Bl[(wn * 64 + i * 16 + lr) * LDA2 + kh * 32 + g * 8]);
      }
#pragma unroll
      for (int i = 0; i < 4; ++i)
#pragma unroll
        for (int j = 0; j < 4; ++j)
          acc[i][j] = __builtin_amdgcn_mfma_f32_16x16x32_bf16(af[i], bfr[j], acc[i][j], 0, 0, 0);
    }
  }

#pragma unroll
  for (int j = 0; j < 4; ++j) {
    int n = nb * 128 + wn * 64 + j * 16 + lr;
    float bv = bf2f(bias[n]);
#pragma unroll
    for (int i = 0; i < 4; ++i) {
      int m0 = mb * 128 + wm * 64 + i * 16 + g * 4;
      float v0 = (acc[i][j][0] + bv) * cscale;
      float v1 = (acc[i][j][1] + bv) * cscale;
      float v2 = (acc[i][j][2] + bv) * cscale;
      float v3 = (acc[i][j][3] + bv) * cscale;
      if (mode == 2) {            // V^T: [B,H,dk,S]; 4 consecutive s -> 8B store
        int b = m0 >> 11, s0 = m0 & (SEQ - 1);
        int h = n >> 6, d = n & (DK - 1);
        uint2 pk;
        pk.x = (unsigned)f2bf(v0) | ((unsigned)f2bf(v1) << 16);
        pk.y = (unsigned)f2bf(v2) | ((unsigned)f2bf(v3) << 16);
        *(uint2*)(&((unsigned short*)Cv)[((long)(b * NH + h) * DK + d) * SEQ + s0]) = pk;
      } else if (mode == 1) {     // [B,H,S,dk]
        int b = m0 >> 11, s0 = m0 & (SEQ - 1);
        int h = n >> 6, d = n & (DK - 1);
        unsigned short* p = &((unsigned short*)Cv)[(((long)(b * NH + h) * SEQ + s0) << 6) + d];
        p[0] = f2bf(v0); p[64] = f2bf(v1); p[128] = f2bf(v2); p[192] = f2bf(v3);
      } else {                    // row-major f32
        float* p = &((float*)Cv)[(long)m0 * DMODEL + n];
        p[0] = v0; p[DMODEL] = v1; p[2 * DMODEL] = v2; p[3 * DMODEL] = v3;
      }
    }
  }
}

// merged Q/K/V projection: 768 blocks, which = blockIdx.x >> 8
__global__ __launch_bounds__(256) void qkv_proj(const unsigned short* __restrict__ Aq,
                                                const unsigned short* __restrict__ Ak,
                                                const unsigned short* __restrict__ Av,
                                                const unsigned short* __restrict__ Wq,
                                                const unsigned short* __restrict__ Wk,
                                                const unsigned short* __restrict__ Wv,
                                                const unsigned short* __restrict__ bq,
                                                const unsigned short* __restrict__ bk,
                                                const unsigned short* __restrict__ bv,
                                                unsigned short* __restrict__ Cq,
                                                unsigned short* __restrict__ Ck,
                                                unsigned short* __restrict__ Cv) {
  __shared__ unsigned short Al[128 * LDA2];
  __shared__ unsigned short Bl[128 * LDA2];
  int which = blockIdx.x >> 8;
  int bid   = blockIdx.x & 255;
  const unsigned short* A = which == 0 ? Aq : (which == 1 ? Ak : Av);
  const unsigned short* W = which == 0 ? Wq : (which == 1 ? Wk : Wv);
  const unsigned short* b = which == 0 ? bq : (which == 1 ? bk : bv);
  unsigned short* C = which == 0 ? Cq : (which == 1 ? Ck : Cv);
  int   mode  = which == 2 ? 2 : 1;
  float scale = which == 0 ? QSCALE : 1.0f;
  gemm_body(A, W, b, C, mode, scale, bid, Al, Bl);
}

__global__ __launch_bounds__(256) void gemm_out(const unsigned short* __restrict__ A,
                                                const unsigned short* __restrict__ W,
                                                const unsigned short* __restrict__ bias,
                                                float* __restrict__ C) {
  __shared__ unsigned short Al[128 * LDA2];
  __shared__ unsigned short Bl[128 * LDA2];
  gemm_body(A, W, bias, C, 0, 1.0f, blockIdx.x, Al, Bl);
}

// ---------------------------------------------------------------- attention
// EXACT r13 compute kernel (twice-validated incl. replays), with ONE change:
// XCD-aware block mapping. id = qb*32 + bh  =>  same-bh blocks differ by 32
// (== 0 mod 8) -> land on the same XCD under round-robin dispatch; 4 bh per
// XCD = 2 MB K/V working set per 4 MB L2 (was: every bh's K/V replicated in
// all 8 L2s -> 70 MB FETCH vs ~25 MB ideal).
#define KVB 64
#define LD 72

__global__ __launch_bounds__(256) void attn(const unsigned short* __restrict__ Q,
                                            const unsigned short* __restrict__ K,
                                            const unsigned short* __restrict__ VT,
                                            const unsigned long long* __restrict__ pm,
                                            unsigned short* __restrict__ O) {
  __shared__ unsigned short Kl[KVB * LD];
  __shared__ unsigned short Vt[DK * LD];       // Vt[d][kv]
  __shared__ unsigned short Pl[4][32 * LD];    // per-wave 32 q-rows
  const int t    = threadIdx.x;
  const int lane = t & 63;
  const int w    = t >> 6;
  const int g    = lane >> 4, lr = lane & 15;
  const int bh   = blockIdx.x & 31;            // XCD swizzle: bh = id % 32
  const int qb   = blockIdx.x >> 5;            // 0..15
  const int b    = bh >> 4, h = bh & 15;
  const long base = (long)bh * SEQ * DK;       // same flat size for K and VT
  const int q0   = qb * 128 + w * 32;          // wave's first q-row

  // Q fragments: qf[qh][kh] (B-operand of swapped QK^T)
  bf16x8 qf[2][2];
#pragma unroll
  for (int qh = 0; qh < 2; ++qh) {
    const unsigned short* qp = Q + base + (long)(q0 + qh * 16 + lr) * DK;
    qf[qh][0] = *(const bf16x8*)(qp + g * 8);
    qf[qh][1] = *(const bf16x8*)(qp + 32 + g * 8);
  }
  float mrun[2] = {NEGI, NEGI}, lrun[2] = {0.f, 0.f};  // log2-domain, q = q0+qh*16+lr
  f32x4 o[2][4] = {};

  for (int kt = 0; kt < SEQ / KVB; ++kt) {
    const int kvbase = kt * KVB;
    __syncthreads();
    // stage K rows [kv][64] — b128 loads/stores
#pragma unroll
    for (int p = 0; p < 2; ++p) {
      int id  = p * 256 + t;
      int row = id >> 3;
      int c8  = (id & 7) << 3;
      bf16x8 kv8 = *(const bf16x8*)(K + base + (long)(kvbase + row) * DK + c8);
      *(bf16x8*)(&Kl[row * LD + c8]) = kv8;
    }
    // stage V^T rows [d][kv-block] — b128 copies
#pragma unroll
    for (int p = 0; p < 2; ++p) {
      int id  = p * 256 + t;
      int row = id >> 3;
      int c8  = (id & 7) << 3;
      bf16x8 vv = *(const bf16x8*)(VT + base + (long)row * SEQ + kvbase + c8);
      *(bf16x8*)(&Vt[row * LD + c8]) = vv;
    }
    __syncthreads();

    // swapped scores: C[kv][q] for both q-groups; K frags read ONCE
    f32x4 sc[2][4];
#pragma unroll
    for (int c = 0; c < 4; ++c) {
      bf16x8 kf0 = *(const bf16x8*)(&Kl[(c * 16 + lr) * LD + g * 8]);
      bf16x8 kf1 = *(const bf16x8*)(&Kl[(c * 16 + lr) * LD + 32 + g * 8]);
#pragma unroll
      for (int qh = 0; qh < 2; ++qh) {
        f32x4 a = {};
        a = __builtin_amdgcn_mfma_f32_16x16x32_bf16(kf0, qf[qh][0], a, 0, 0, 0);
        a = __builtin_amdgcn_mfma_f32_16x16x32_bf16(kf1, qf[qh][1], a, 0, 0, 0);
        sc[qh][c] = a;
      }
    }

    unsigned short* P = &Pl[w][0];
#pragma unroll
    for (int qh = 0; qh < 2; ++qh) {
      const unsigned long long mw = pm[((long)b * SEQ + q0 + qh * 16 + lr) * 32 + kt];
      float s[4][4];
      float mt = NEGI;
#pragma unroll
      for (int c = 0; c < 4; ++c)
#pragma unroll
        for (int r = 0; r < 4; ++r) {
          int kvi = c * 16 + g * 4 + r;
          float v = ((mw >> kvi) & 1ull) ? sc[qh][c][r] : -1e9f;
          s[c][r] = v;
          mt = fmaxf(mt, v);
        }
      mt = fmaxf(mt, __shfl_xor(mt, 16, 64));
      mt = fmaxf(mt, __shfl_xor(mt, 32, 64));

      int need = __any(mt > mrun[qh] + 5.0f);   // defer-max (T13), log2 units
      float mn = mrun[qh], corr = 1.0f;
      if (need) { mn = fmaxf(mrun[qh], mt); corr = __builtin_amdgcn_exp2f(mrun[qh] - mn); mrun[qh] = mn; }

      float pf[4][4];
      float rs = 0.f;
#pragma unroll
      for (int c = 0; c < 4; ++c)
#pragma unroll
        for (int r = 0; r < 4; ++r) {
          float p_ = __builtin_amdgcn_exp2f(s[c][r] - mn);
          pf[c][r] = p_;
          rs += p_;
        }
      rs += __shfl_xor(rs, 16, 64);
      rs += __shfl_xor(rs, 32, 64);

      if (need) {
        lrun[qh] = lrun[qh] * corr + rs;
#pragma unroll
        for (int r = 0; r < 4; ++r) {
          float cq = __shfl(corr, (lane >> 4) * 4 + r, 64);  // corr of q-row g*4+r
#pragma unroll
          for (int dt = 0; dt < 4; ++dt) o[qh][dt][r] *= cq;
        }
      } else {
        lrun[qh] += rs;
      }

      // P store (A-fragment layout): row q-local = qh*16+lr, kv cols
#pragma unroll
      for (int c = 0; c < 4; ++c) {
        uint2 pk;
        pk.x = cvtpk(pf[c][0], pf[c][1]);
        pk.y = cvtpk(pf[c][2], pf[c][3]);
        *(uint2*)(&P[(qh * 16 + lr) * LD + c * 16 + g * 4]) = pk;
      }
    }
    __syncthreads();   // fence P stores vs vector re-reads (r8-proven)
    // PV: V fragments read ONCE, used by both q-groups
#pragma unroll
    for (int c32 = 0; c32 < 2; ++c32) {
      bf16x8 pf0 = *(const bf16x8*)(&P[lr * LD + c32 * 32 + g * 8]);
      bf16x8 pf1 = *(const bf16x8*)(&P[(16 + lr) * LD + c32 * 32 + g * 8]);
#pragma unroll
      for (int dt = 0; dt < 4; ++dt) {
        bf16x8 vf = *(const bf16x8*)(&Vt[(dt * 16 + lr) * LD + c32 * 32 + g * 8]);
        o[0][dt] = __builtin_amdgcn_mfma_f32_16x16x32_bf16(pf0, vf, o[0][dt], 0, 0, 0);
        o[1][dt] = __builtin_amdgcn_mfma_f32_16x16x32_bf16(pf1, vf, o[1][dt], 0, 0, 0);
      }
    }
  }
#pragma unroll
  for (int qh = 0; qh < 2; ++qh) {
    float inv = 1.0f / lrun[qh];
#pragma unroll
    for (int r = 0; r < 4; ++r) {
      float iq = __shfl(inv, (lane >> 4) * 4 + r, 64);
      int q = q0 + qh * 16 + g * 4 + r;
      unsigned short* op = O + ((long)(b * SEQ + q) * DMODEL) + h * DK;
#pragma unroll
      for (int dt = 0; dt < 4; ++dt) op[dt * 16 + lr] = f2bf(o[qh][dt][r] * iq);
    }
  }
}

// ---------------------------------------------------------------- launch
extern "C" void kernel_launch(void* const* d_in, const int* in_sizes, int n_in,
                              void* d_out, int out_size, void* d_ws, size_t ws_size,
                              hipStream_t stream) {
  const int* maskp = (const int*)d_in[3];
  float* out = (float*)d_out;

  char* ws = (char*)d_ws;
  const long MB = 1 << 20;
  unsigned long long* pm = (unsigned long long*)ws;             // 1 MB
  unsigned short* Qc  = (unsigned short*)(ws + 1 * MB);         // 8 MB each
  unsigned short* Kc  = (unsigned short*)(ws + 9 * MB);
  unsigned short* Vc  = (unsigned short*)(ws + 17 * MB);
  unsigned short* Wqc = (unsigned short*)(ws + 25 * MB);        // 2 MB each
  unsigned short* Wkc = (unsigned short*)(ws + 27 * MB);
  unsigned short* Wvc = (unsigned short*)(ws + 29 * MB);
  unsigned short* Woc = (unsigned short*)(ws + 31 * MB);
  unsigned short* bqc = (unsigned short*)(ws + 33 * MB);        // 2 KB each
  unsigned short* bkc = (unsigned short*)(ws + 33 * MB + 4096);
  unsigned short* bvc = (unsigned short*)(ws + 33 * MB + 8192);
  unsigned short* boc = (unsigned short*)(ws + 33 * MB + 12288);
  unsigned short* Qb  = (unsigned short*)(ws + 35 * MB);        // 8 MB each
  unsigned short* Kb  = (unsigned short*)(ws + 43 * MB);
  unsigned short* Vb  = (unsigned short*)(ws + 51 * MB);        // holds V^T
  unsigned short* Ab  = (unsigned short*)(ws + 59 * MB);

  const long nQKV8 = (long)MROWS * DMODEL / 8;   // 524288
  const long nW8   = (long)DMODEL * DMODEL / 8;  // 131072
  convert3<<<1536, 256, 0, stream>>>((const float*)d_in[0], (const float*)d_in[1],
                                     (const float*)d_in[2], Qc, Kc, Vc, nQKV8, 512);
  convert4<<<512, 256, 0, stream>>>((const float*)d_in[4], (const float*)d_in[6],
                                    (const float*)d_in[8], (const float*)d_in[10],
                                    Wqc, Wkc, Wvc, Woc, nW8, 128);
  convert4<<<4, 256, 0, stream>>>((const float*)d_in[5], (const float*)d_in[7],
                                  (const float*)d_in[9], (const float*)d_in[11],
                                  bqc, bkc, bvc, boc, DMODEL / 8, 1);

  const int nwords = BATCH * SEQ * (SEQ / 64);  // 131072
  pack_mask<<<512, 256, 0, stream>>>(maskp, pm, nwords);

  qkv_proj<<<768, 256, 0, stream>>>(Qc, Kc, Vc, Wqc, Wkc, Wvc,
                                    bqc, bkc, bvc, Qb, Kb, Vb);

  attn<<<BATCH * NH * (SEQ / 128), 256, 0, stream>>>(Qb, Kb, Vb, pm, Ab);

  gemm_out<<<256, 256, 0, stream>>>(Ab, Woc, boc, out);
}